// Round 5
// baseline (22188.872 us; speedup 1.0000x reference)
//
#include <hip/hip_runtime.h>
#include <stdio.h>
#include <stdint.h>

// Problem constants
#define BB 32      // batch
#define TT 1024    // time
#define DH 512     // rnn1 hidden
#define ND 64      // nodes / rnn2 hidden
#define TC 128     // time-chunk for xp materialization

typedef short bf16x8 __attribute__((ext_vector_type(8)));
typedef float f32x4  __attribute__((ext_vector_type(4)));

static __device__ __forceinline__ float bf2f(unsigned short u) {
    union { unsigned int i; float f; } v; v.i = ((unsigned int)u) << 16; return v.f;
}
static __device__ __forceinline__ unsigned short f2bf_rne(float f) {
    union { float f; unsigned int i; } v; v.f = f;
    unsigned int u = v.i;
    return (unsigned short)((u + 0x7fffu + ((u >> 16) & 1u)) >> 16);
}
static __device__ __forceinline__ float sigm(float x) { return 1.f / (1.f + __expf(-x)); }
static __device__ __forceinline__ float tanhs(float x) {
    float ax = fabsf(x);
    float e = __expf(-2.f * ax);
    float t = (1.f - e) / (1.f + e);
    return x < 0.f ? -t : t;
}

// ---------------- fp32 -> bf16 convert (vectorized x4) ----------------
__global__ void k_f2bf(const float* __restrict__ src, unsigned short* __restrict__ dst, int n4) {
    int i = blockIdx.x * blockDim.x + threadIdx.x;
    if (i < n4) {
        float4 v = ((const float4*)src)[i];
        ushort4 o;
        o.x = f2bf_rne(v.x); o.y = f2bf_rne(v.y); o.z = f2bf_rne(v.z); o.w = f2bf_rne(v.w);
        ((ushort4*)dst)[i] = o;
    }
}

// ---------------- bias sum ----------------
__global__ void k_bsum(const float* __restrict__ a, const float* __restrict__ b,
                       float* __restrict__ d, int n) {
    int i = blockIdx.x * blockDim.x + threadIdx.x;
    if (i < n) d[i] = a[i] + b[i];
}

// ---------------- full GEMM for rnn2 projection ----------------
// out row' = t*32+b, N=256, K=1024
__global__ __launch_bounds__(256) void k_gemm(
    const unsigned short* __restrict__ A,
    const unsigned short* __restrict__ W,
    const float* __restrict__ bias,
    unsigned short* __restrict__ out,
    int N, int K)
{
    __shared__ unsigned short lw[128 * 72];
    __shared__ unsigned short la[128 * 72];
    const int tid = threadIdx.x;
    const int n0 = blockIdx.x * 128;
    const int m0 = blockIdx.y * 128;
    const int lane = tid & 63, wv = tid >> 6;
    const int q = lane >> 4, lr = lane & 15;
    const int wn = wv & 1, wm = wv >> 1;

    f32x4 acc[4][4];
#pragma unroll
    for (int i = 0; i < 4; i++)
#pragma unroll
        for (int j = 0; j < 4; j++) acc[i][j] = (f32x4){0.f, 0.f, 0.f, 0.f};

    const int srow = tid >> 1, shalf = tid & 1;
    for (int k0 = 0; k0 < K; k0 += 64) {
        const uint4* gw = (const uint4*)(W + (size_t)(n0 + srow) * K + k0 + shalf * 32);
        const uint4* ga = (const uint4*)(A + (size_t)(m0 + srow) * K + k0 + shalf * 32);
        uint4 wld[4], ald[4];
#pragma unroll
        for (int j = 0; j < 4; j++) { wld[j] = gw[j]; ald[j] = ga[j]; }
        __syncthreads();
#pragma unroll
        for (int j = 0; j < 4; j++) {
            ((uint4*)lw)[srow * 9 + shalf * 4 + j] = wld[j];
            ((uint4*)la)[srow * 9 + shalf * 4 + j] = ald[j];
        }
        __syncthreads();
#pragma unroll
        for (int ks = 0; ks < 2; ks++) {
            bf16x8 fw[4], fa[4];
#pragma unroll
            for (int i = 0; i < 4; i++)
                fw[i] = *(const bf16x8*)&lw[(64 * wn + 16 * i + lr) * 72 + ks * 32 + q * 8];
#pragma unroll
            for (int j = 0; j < 4; j++)
                fa[j] = *(const bf16x8*)&la[(64 * wm + 16 * j + lr) * 72 + ks * 32 + q * 8];
#pragma unroll
            for (int i = 0; i < 4; i++)
#pragma unroll
                for (int j = 0; j < 4; j++)
                    acc[i][j] = __builtin_amdgcn_mfma_f32_16x16x32_bf16(fw[i], fa[j], acc[i][j], 0, 0, 0);
        }
    }
#pragma unroll
    for (int i = 0; i < 4; i++) {
        const int nb = n0 + 64 * wn + 16 * i + q * 4;
        const float4 bb = *(const float4*)(bias + nb);
#pragma unroll
        for (int j = 0; j < 4; j++) {
            const int m = m0 + 64 * wm + 16 * j + lr;
            const int rowp = ((m & 1023) << 5) | (m >> 10);  // t*32 + b
            ushort4 o;
            o.x = f2bf_rne(acc[i][j][0] + bb.x);
            o.y = f2bf_rne(acc[i][j][1] + bb.y);
            o.z = f2bf_rne(acc[i][j][2] + bb.z);
            o.w = f2bf_rne(acc[i][j][3] + bb.w);
            *(ushort4*)(out + (size_t)rowp * N + nb) = o;
        }
    }
}

// ---------------- fused per-layer persistent kernel ----------------
// grid = 192 WGs x 512 thr, 158464 B dynamic LDS -> 1 WG/CU, all co-resident.
// WGs 0..63: persistent RNN (dir = b&1, bg = (b>>1)&1, cs = b>>2; 32 cols/WG).
//   h-exchange: producer sc1 packed stores -> flag; consumer flag poll ->
//   fence(acquire,agent) -> PLAIN pipelined uint4 loads (one round trip).
// WGs 64..191: gemm workers, 2 engines of 256 thr each, producing xpc chunks.
// ctl: [0..127] chunkready[c]*16, [128] rnnprog, [256..] stepflag[((d*2+bg)*16+cs)*16].
__global__ __launch_bounds__(512) void k_layer(
    const unsigned short* A,                  // layer input [32][1024][K] bf16
    const unsigned short* wih,                // [4096][K] bf16
    const float* bias,                        // [4096] f32 (b_ih+b_hh)
    const unsigned short* whh,                // [2][2048][512] bf16
    unsigned short* __restrict__ outb,        // [32][1024][1024] bf16
    unsigned short* xpc,                      // 2 chunks of [TC][32][4096] bf16
    unsigned short* hbuf,                     // [2dir][2par][32][512] bf16
    unsigned int* ctl, int K)
{
    extern __shared__ unsigned short smem[];
    const int tid = threadIdx.x;
    const int bid = blockIdx.x;
    unsigned int* chunkready = ctl;
    unsigned int* rnnprog = ctl + 128;
    unsigned int* stepflag = ctl + 256;

    if (bid < 64) {
        // =================== RNN role ===================
        unsigned short* lw = smem;                          // 128*520
        unsigned short* lh = smem + 128 * 520;              // 16*520
        float* lg = (float*)(smem + 128 * 520 + 16 * 520);  // 128*17
        const int dir = bid & 1;
        const int bg = (bid >> 1) & 1;
        const int cs = bid >> 2;
        const int c0 = cs * 32, b0 = bg * 16;
        const int lane = tid & 63, wv = tid >> 6;
        const int q = lane >> 4, lr = lane & 15;

        // one-time: stage weight slice into padded LDS
        for (int i = tid; i < 128 * 64; i += 512) {
            int row = i >> 6, ch = i & 63;
            int ty = row >> 5, cc = row & 31;
            ((uint4*)lw)[row * 65 + ch] =
                *(const uint4*)(whh + ((size_t)(dir * 2048 + ty * 512 + c0 + cc) * 512 + ch * 8));
        }
        const int xb = tid >> 5;   // batch in group 0..15
        const int xc = tid & 31;   // col in slice 0..31
        float cstate = 0.f;
        unsigned int* myflag = stepflag + ((dir * 2 + bg) * 16 + cs) * 16;
        const unsigned int* grpflag = stepflag + (dir * 2 + bg) * 256;
        __syncthreads();

        for (int s = 0; s < TT; ++s) {
            if ((s & (TC - 1)) == 0) {
                const int c = s >> 7;
                if (tid == 0) {
                    while (__hip_atomic_load(&chunkready[c * 16], __ATOMIC_RELAXED,
                                             __HIP_MEMORY_SCOPE_AGENT) < 128u)
                        __builtin_amdgcn_s_sleep(8);
                }
                __syncthreads();
                __builtin_amdgcn_fence(__ATOMIC_ACQUIRE, "agent");  // invalidate stale xpc
            }
            const unsigned short* xpb = xpc + (size_t)((s >> 7) & 1) * (TC * 32ull * 4096);
            const int t = dir ? (TT - 1 - s) : s;
            // prefetch xp (independent of h -> overlaps flag poll)
            const unsigned short* xpp = xpb + ((size_t)((s & (TC - 1)) * 32 + b0 + xb) * 4096)
                                       + dir * 2048 + c0 + xc;
            unsigned short x0 = xpp[0], x1 = xpp[512], x2 = xpp[1024], x3 = xpp[1536];

            if (s > 0) {
                // 1) poll group flags: lanes 0..15 of wave 0, parallel
                if (wv == 0) {
                    const unsigned int tgt = (unsigned int)s;
                    const unsigned int* fl = grpflag + (lane & 15) * 16;
                    for (;;) {
                        unsigned int v = (lane < 16)
                            ? __hip_atomic_load(fl, __ATOMIC_RELAXED, __HIP_MEMORY_SCOPE_AGENT)
                            : tgt;
                        if (__all((int)(v >= tgt))) break;
                    }
                }
                __syncthreads();
                // 2) acquire: invalidate L1/L2 so plain loads see fresh h
                __builtin_amdgcn_fence(__ATOMIC_ACQUIRE, "agent");
                // 3) gather h(s-1): 16 KB via plain pipelined uint4 loads
                {
                    const int pp = (s & 1) ^ 1;
                    const uint4* hp = (const uint4*)(hbuf + ((size_t)(dir * 2 + pp) * 32 + b0) * 512);
                    uint4 u0 = hp[tid];
                    uint4 u1 = hp[tid + 512];
                    *(uint4*)&lh[(tid >> 6) * 520 + (tid & 63) * 8] = u0;
                    *(uint4*)&lh[((tid >> 6) + 8) * 520 + (tid & 63) * 8] = u1;
                }
                __syncthreads();
                // 4) MFMA: gates(s) partials
                f32x4 acc = (f32x4){0.f, 0.f, 0.f, 0.f};
                const unsigned short* lwr = lw + (16 * wv + lr) * 520;
                const unsigned short* lhr = lh + lr * 520;
#pragma unroll
                for (int ks = 0; ks < 16; ++ks) {
                    bf16x8 a = *(const bf16x8*)(lwr + ks * 32 + q * 8);
                    bf16x8 b = *(const bf16x8*)(lhr + ks * 32 + q * 8);
                    acc = __builtin_amdgcn_mfma_f32_16x16x32_bf16(a, b, acc, 0, 0, 0);
                }
#pragma unroll
                for (int r = 0; r < 4; ++r)
                    lg[(16 * wv + q * 4 + r) * 17 + lr] = acc[r];
                __syncthreads();
            }

            // cell update: thread owns (batch xb, col xc)
            unsigned short h16;
            {
                float gi = bf2f(x0) + (s > 0 ? lg[(0 * 32 + xc) * 17 + xb] : 0.f);
                float gf = bf2f(x1) + (s > 0 ? lg[(1 * 32 + xc) * 17 + xb] : 0.f);
                float gg = bf2f(x2) + (s > 0 ? lg[(2 * 32 + xc) * 17 + xb] : 0.f);
                float go = bf2f(x3) + (s > 0 ? lg[(3 * 32 + xc) * 17 + xb] : 0.f);
                float ig = sigm(gi), fg = sigm(gf), cg = tanhs(gg), og = sigm(go);
                cstate = fg * cstate + ig * cg;
                float h = og * tanhs(cstate);
                h16 = f2bf_rne(h);
                // h -> hbuf: sc1 (write-through) packed stores, fire-and-forget
                unsigned int hv = h16;
                unsigned int other = __shfl_xor((int)hv, 1);
                if ((tid & 1) == 0) {
                    size_t idx = ((size_t)(dir * 2 + (s & 1)) * 32 + b0 + xb) * 512 + c0 + xc;
                    unsigned int packed = hv | (other << 16);
                    __hip_atomic_store((unsigned int*)hbuf + (idx >> 1), packed,
                                       __ATOMIC_RELAXED, __HIP_MEMORY_SCOPE_AGENT);
                }
            }
            // barrier drains every thread's h stores (vmcnt(0) before s_barrier)
            __syncthreads();
            if (tid == 0)
                __hip_atomic_store(myflag, (unsigned int)(s + 1),
                                   __ATOMIC_RELAXED, __HIP_MEMORY_SCOPE_AGENT);
            if ((s & (TC - 1)) == (TC - 1) && tid == 0)
                __hip_atomic_fetch_add(rnnprog, 1u, __ATOMIC_RELAXED, __HIP_MEMORY_SCOPE_AGENT);
            // layer output off the critical path (drains during next step's poll)
            outb[((size_t)(b0 + xb) * TT + t) * 1024 + dir * 512 + c0 + xc] = h16;
        }
    } else {
        // =================== GEMM worker role ===================
        const int w = bid - 64;               // 0..127
        const int engine = tid >> 8;          // 0/1
        const int etid = tid & 255;
        unsigned short* lw = smem + engine * 18432;   // 128*72 shorts
        unsigned short* la = lw + 9216;
        const int lane = etid & 63, wv = etid >> 6;
        const int q = lane >> 4, lr = lane & 15;
        const int wn = wv & 1, wm = wv >> 1;
        const int srow = etid >> 1, shalf = etid & 1;

        for (int c = 0; c < 8; ++c) {
            if (c >= 2) {
                // back-pressure: don't overwrite buffer until rnn consumed chunk c-2
                if (tid == 0) {
                    unsigned int tgt = 64u * (unsigned int)(c - 1);
                    while (__hip_atomic_load(rnnprog, __ATOMIC_RELAXED,
                                             __HIP_MEMORY_SCOPE_AGENT) < tgt)
                        __builtin_amdgcn_s_sleep(8);
                }
                __syncthreads();
            }
            unsigned short* xpb = xpc + (size_t)(c & 1) * (TC * 32ull * 4096);
            for (int jt = 0; jt < 4; ++jt) {
                const int tau = (w * 2 + engine) + 256 * jt;    // 0..1023
                const int dir = tau >> 9, rem = tau & 511;
                const int b = rem >> 4, nx = rem & 15;
                const int t0 = dir ? (TT - c * TC - TC) : (c * TC);
                const int n0 = dir * 2048 + nx * 128;
                const int m0 = b * TT + t0;
                f32x4 acc[4][4];
#pragma unroll
                for (int i = 0; i < 4; i++)
#pragma unroll
                    for (int j = 0; j < 4; j++) acc[i][j] = (f32x4){0.f, 0.f, 0.f, 0.f};

                for (int k0 = 0; k0 < K; k0 += 64) {
                    const uint4* gw = (const uint4*)(wih + (size_t)(n0 + srow) * K + k0 + shalf * 32);
                    const uint4* ga = (const uint4*)(A + (size_t)(m0 + srow) * K + k0 + shalf * 32);
                    uint4 wld[4], ald[4];
#pragma unroll
                    for (int j = 0; j < 4; j++) { wld[j] = gw[j]; ald[j] = ga[j]; }
                    __syncthreads();
#pragma unroll
                    for (int j = 0; j < 4; j++) {
                        ((uint4*)lw)[srow * 9 + shalf * 4 + j] = wld[j];
                        ((uint4*)la)[srow * 9 + shalf * 4 + j] = ald[j];
                    }
                    __syncthreads();
#pragma unroll
                    for (int ks = 0; ks < 2; ks++) {
                        bf16x8 fw[4], fa[4];
#pragma unroll
                        for (int i = 0; i < 4; i++)
                            fw[i] = *(const bf16x8*)&lw[(64 * wn + 16 * i + lr) * 72 + ks * 32 + q * 8];
#pragma unroll
                        for (int j = 0; j < 4; j++)
                            fa[j] = *(const bf16x8*)&la[(64 * wm + 16 * j + lr) * 72 + ks * 32 + q * 8];
#pragma unroll
                        for (int i = 0; i < 4; i++)
#pragma unroll
                            for (int j = 0; j < 4; j++)
                                acc[i][j] = __builtin_amdgcn_mfma_f32_16x16x32_bf16(fw[i], fa[j], acc[i][j], 0, 0, 0);
                    }
                }
#pragma unroll
                for (int i = 0; i < 4; i++) {
                    const int nb = n0 + 64 * wn + 16 * i + q * 4;
                    const float4 bb = *(const float4*)(bias + nb);
#pragma unroll
                    for (int j = 0; j < 4; j++) {
                        const int dm = 64 * wm + 16 * j + lr;          // t = t0 + dm
                        const int islot = dir ? (TC - 1 - dm) : dm;    // step-within-chunk
                        ushort4 o;
                        o.x = f2bf_rne(acc[i][j][0] + bb.x);
                        o.y = f2bf_rne(acc[i][j][1] + bb.y);
                        o.z = f2bf_rne(acc[i][j][2] + bb.z);
                        o.w = f2bf_rne(acc[i][j][3] + bb.w);
                        *(ushort4*)(xpb + ((size_t)islot * 32 + b) * 4096 + nb) = o;
                    }
                }
            }
            // publish chunk: write back dirty L2 lines, then signal
            __builtin_amdgcn_fence(__ATOMIC_RELEASE, "agent");
            __syncthreads();
            if (tid == 0)
                __hip_atomic_fetch_add(&chunkready[c * 16], 1u,
                                       __ATOMIC_RELEASE, __HIP_MEMORY_SCOPE_AGENT);
        }
    }
}

// ---------------- rnn2: unidirectional, H=64; register-resident gates ----------------
__global__ __launch_bounds__(512) void k_rnn2(
    const unsigned short* __restrict__ xp2,   // [t*32+b][256] bf16
    const unsigned short* __restrict__ whh2,  // [256][64] bf16
    float* __restrict__ out)                  // [B][T][64] f32
{
    __shared__ unsigned short lw[256 * 72];
    __shared__ unsigned short lh[2][16 * 68];
    const int tid = threadIdx.x;
    const int b0 = blockIdx.x * 16;
    const int lane = tid & 63, wv = tid >> 6;
    const int q = lane >> 4, l = lane & 15;

    for (int i = tid; i < 256 * 8; i += 512) {
        int row = i >> 3, ch = i & 7;
        ((uint4*)lw)[row * 9 + ch] = *(const uint4*)(whh2 + (size_t)row * 64 + ch * 8);
    }
    __syncthreads();

    if (wv < 4) {
        const int cbase = wv * 16 + q * 4;
        float cst[4] = {0.f, 0.f, 0.f, 0.f};
        for (int s = 0; s < TT; ++s) {
            const unsigned short* xr = xp2 + (size_t)(s * 32 + b0 + l) * 256 + cbase;
            ushort4 xv0 = *(const ushort4*)(xr);
            ushort4 xv1 = *(const ushort4*)(xr + 64);
            ushort4 xv2 = *(const ushort4*)(xr + 128);
            ushort4 xv3 = *(const ushort4*)(xr + 192);
            f32x4 acc[4];
            if (s > 0) {
                const unsigned short* lhr = lh[(s & 1) ^ 1] + l * 68;
                bf16x8 hb0 = *(const bf16x8*)(lhr + q * 8);
                bf16x8 hb1 = *(const bf16x8*)(lhr + 32 + q * 8);
#pragma unroll
                for (int ty = 0; ty < 4; ++ty) {
                    const unsigned short* lwr = lw + (size_t)(ty * 64 + wv * 16 + l) * 72;
                    bf16x8 a0 = *(const bf16x8*)(lwr + q * 8);
                    bf16x8 a1 = *(const bf16x8*)(lwr + 32 + q * 8);
                    f32x4 tacc = (f32x4){0.f, 0.f, 0.f, 0.f};
                    tacc = __builtin_amdgcn_mfma_f32_16x16x32_bf16(a0, hb0, tacc, 0, 0, 0);
                    tacc = __builtin_amdgcn_mfma_f32_16x16x32_bf16(a1, hb1, tacc, 0, 0, 0);
                    acc[ty] = tacc;
                }
            } else {
#pragma unroll
                for (int ty = 0; ty < 4; ++ty) acc[ty] = (f32x4){0.f, 0.f, 0.f, 0.f};
            }
            ushort4 ho; float4 oo;
            const unsigned short* xs0 = (const unsigned short*)&xv0;
            const unsigned short* xs1 = (const unsigned short*)&xv1;
            const unsigned short* xs2 = (const unsigned short*)&xv2;
            const unsigned short* xs3 = (const unsigned short*)&xv3;
#pragma unroll
            for (int r = 0; r < 4; ++r) {
                float gi = bf2f(xs0[r]) + acc[0][r];
                float gf = bf2f(xs1[r]) + acc[1][r];
                float gg = bf2f(xs2[r]) + acc[2][r];
                float go = bf2f(xs3[r]) + acc[3][r];
                float ig = sigm(gi), fg = sigm(gf), cg = tanhs(gg), og = sigm(go);
                cst[r] = fg * cst[r] + ig * cg;
                float h = og * tanhs(cst[r]);
                ((float*)&oo)[r] = 40.f * h;
                ((unsigned short*)&ho)[r] = f2bf_rne(h);
            }
            *(ushort4*)(lh[s & 1] + l * 68 + cbase) = ho;
            *(float4*)(out + ((size_t)(b0 + l) * TT + s) * 64 + cbase) = oo;
            __syncthreads();
        }
    } else {
        for (int s = 0; s < TT; ++s) __syncthreads();
    }
}

// ---------------- host launch ----------------
extern "C" void kernel_launch(void* const* d_in, const int* in_sizes, int n_in,
                              void* d_out, int out_size, void* d_ws, size_t ws_size,
                              hipStream_t stream) {
    (void)in_sizes; (void)n_in; (void)out_size;
    const float* x     = (const float*)d_in[0];
    const float* Wih0  = (const float*)d_in[1];
    const float* Whh0  = (const float*)d_in[2];
    const float* bih0  = (const float*)d_in[3];
    const float* bhh0  = (const float*)d_in[4];
    const float* Wih12 = (const float*)d_in[5];
    const float* Whh12 = (const float*)d_in[6];
    const float* bih12 = (const float*)d_in[7];
    const float* bhh12 = (const float*)d_in[8];
    const float* Wih2  = (const float*)d_in[9];
    const float* Whh2  = (const float*)d_in[10];
    const float* bih2  = (const float*)d_in[11];
    const float* bhh2  = (const float*)d_in[12];
    float* out = (float*)d_out;

    char* ws = (char*)d_ws;
    size_t off = 0;
    auto alloc = [&](size_t sz) { char* p = ws + off; off += (sz + 255) & ~(size_t)255; return p; };
    unsigned short* actA  = (unsigned short*)alloc(33554432ull * 2);        // 64 MB
    unsigned short* actB  = (unsigned short*)alloc(33554432ull * 2);        // 64 MB
    unsigned short* xpc   = (unsigned short*)alloc(2ull * TC * 32 * 4096 * 2); // 64 MB (dbuf)
    unsigned short* xbf   = (unsigned short*)alloc(2097152ull * 2);
    unsigned short* wihc  = (unsigned short*)alloc(4194304ull * 2);         // per-layer W_ih
    unsigned short* whhc  = (unsigned short*)alloc(2097152ull * 2);         // per-layer W_hh
    unsigned short* wih2b = (unsigned short*)alloc(262144ull * 2);
    unsigned short* whh2b = (unsigned short*)alloc(16384ull * 2);
    float* bs  = (float*)alloc(4096 * 4);
    float* bs2 = (float*)alloc(256 * 4);
    unsigned short* hbuf = (unsigned short*)alloc(2ull * 2 * 32 * 512 * 2);
    unsigned int* ctrl = (unsigned int*)alloc(16384);

    if (ws_size < off) {
        fprintf(stderr, "[kernel_launch] ws_size=%zu < needed=%zu — aborting cleanly\n", ws_size, off);
        return;
    }

    auto cvt = [&](const float* s, unsigned short* d, int n) {
        int n4 = n / 4;
        k_f2bf<<<(n4 + 255) / 256, 256, 0, stream>>>(s, d, n4);
    };
    cvt(x, xbf, 2097152);
    cvt(Wih2, wih2b, 262144);
    cvt(Whh2, whh2b, 16384);
    k_bsum<<<1, 256, 0, stream>>>(bih2, bhh2, bs2, 256);

    hipError_t rc = hipFuncSetAttribute(reinterpret_cast<const void*>(k_layer),
                                        hipFuncAttributeMaxDynamicSharedMemorySize, 160 * 1024);
    if (rc != hipSuccess) fprintf(stderr, "[kernel_launch] hipFuncSetAttribute rc=%d\n", (int)rc);
    const size_t layer_lds = (size_t)(128 * 520 + 16 * 520) * 2 + (size_t)128 * 17 * 4;  // 158464 B

    for (int l = 0; l < 3; ++l) {
        const unsigned short* Abuf;
        unsigned short* Obuf;
        int K;
        if (l == 0) {
            cvt(Wih0, wihc, 262144);
            cvt(Whh0, whhc, 2097152);
            k_bsum<<<16, 256, 0, stream>>>(bih0, bhh0, bs, 4096);
            Abuf = xbf; Obuf = actA; K = 64;
        } else {
            cvt(Wih12 + (size_t)(l - 1) * 4194304, wihc, 4194304);
            cvt(Whh12 + (size_t)(l - 1) * 2097152, whhc, 2097152);
            k_bsum<<<16, 256, 0, stream>>>(bih12 + (l - 1) * 4096, bhh12 + (l - 1) * 4096, bs, 4096);
            Abuf = (l == 1) ? actA : actB;
            Obuf = (l == 1) ? actB : actA;
            K = 1024;
        }
        hipMemsetAsync(ctrl, 0, 16384, stream);
        k_layer<<<192, 512, layer_lds, stream>>>(Abuf, wihc, bs, whhc, Obuf, xpc, hbuf, ctrl, K);
    }

    // rnn2: projection (16 MB, fits in xpc) then register-resident scan
    k_gemm<<<dim3(2, 256), 256, 0, stream>>>(actA, wih2b, bs2, xpc, 256, 1024);
    k_rnn2<<<2, 512, 0, stream>>>(xpc, whh2b, out);
}

// Round 6
// 11455.573 us; speedup vs baseline: 1.9369x; 1.9369x over previous
//
#include <hip/hip_runtime.h>
#include <stdio.h>
#include <stdint.h>

// Problem constants
#define BB 32      // batch
#define TT 1024    // time
#define DH 512     // rnn1 hidden
#define ND 64      // nodes / rnn2 hidden
#define TC 128     // time-chunk for xp materialization

typedef short bf16x8 __attribute__((ext_vector_type(8)));
typedef float f32x4  __attribute__((ext_vector_type(4)));

static __device__ __forceinline__ float bf2f(unsigned short u) {
    union { unsigned int i; float f; } v; v.i = ((unsigned int)u) << 16; return v.f;
}
static __device__ __forceinline__ unsigned short f2bf_rne(float f) {
    union { float f; unsigned int i; } v; v.f = f;
    unsigned int u = v.i;
    return (unsigned short)((u + 0x7fffu + ((u >> 16) & 1u)) >> 16);
}
static __device__ __forceinline__ float sigm(float x) { return 1.f / (1.f + __expf(-x)); }
static __device__ __forceinline__ float tanhs(float x) {
    float ax = fabsf(x);
    float e = __expf(-2.f * ax);
    float t = (1.f - e) / (1.f + e);
    return x < 0.f ? -t : t;
}

// ---------------- fp32 -> bf16 convert (vectorized x4) ----------------
__global__ void k_f2bf(const float* __restrict__ src, unsigned short* __restrict__ dst, int n4) {
    int i = blockIdx.x * blockDim.x + threadIdx.x;
    if (i < n4) {
        float4 v = ((const float4*)src)[i];
        ushort4 o;
        o.x = f2bf_rne(v.x); o.y = f2bf_rne(v.y); o.z = f2bf_rne(v.z); o.w = f2bf_rne(v.w);
        ((ushort4*)dst)[i] = o;
    }
}

// ---------------- bias sum ----------------
__global__ void k_bsum(const float* __restrict__ a, const float* __restrict__ b,
                       float* __restrict__ d, int n) {
    int i = blockIdx.x * blockDim.x + threadIdx.x;
    if (i < n) d[i] = a[i] + b[i];
}

// ---------------- full GEMM for rnn2 projection ----------------
// out row' = t*32+b, N=256, K=1024
__global__ __launch_bounds__(256) void k_gemm(
    const unsigned short* __restrict__ A,
    const unsigned short* __restrict__ W,
    const float* __restrict__ bias,
    unsigned short* __restrict__ out,
    int N, int K)
{
    __shared__ unsigned short lw[128 * 72];
    __shared__ unsigned short la[128 * 72];
    const int tid = threadIdx.x;
    const int n0 = blockIdx.x * 128;
    const int m0 = blockIdx.y * 128;
    const int lane = tid & 63, wv = tid >> 6;
    const int q = lane >> 4, lr = lane & 15;
    const int wn = wv & 1, wm = wv >> 1;

    f32x4 acc[4][4];
#pragma unroll
    for (int i = 0; i < 4; i++)
#pragma unroll
        for (int j = 0; j < 4; j++) acc[i][j] = (f32x4){0.f, 0.f, 0.f, 0.f};

    const int srow = tid >> 1, shalf = tid & 1;
    for (int k0 = 0; k0 < K; k0 += 64) {
        const uint4* gw = (const uint4*)(W + (size_t)(n0 + srow) * K + k0 + shalf * 32);
        const uint4* ga = (const uint4*)(A + (size_t)(m0 + srow) * K + k0 + shalf * 32);
        uint4 wld[4], ald[4];
#pragma unroll
        for (int j = 0; j < 4; j++) { wld[j] = gw[j]; ald[j] = ga[j]; }
        __syncthreads();
#pragma unroll
        for (int j = 0; j < 4; j++) {
            ((uint4*)lw)[srow * 9 + shalf * 4 + j] = wld[j];
            ((uint4*)la)[srow * 9 + shalf * 4 + j] = ald[j];
        }
        __syncthreads();
#pragma unroll
        for (int ks = 0; ks < 2; ks++) {
            bf16x8 fw[4], fa[4];
#pragma unroll
            for (int i = 0; i < 4; i++)
                fw[i] = *(const bf16x8*)&lw[(64 * wn + 16 * i + lr) * 72 + ks * 32 + q * 8];
#pragma unroll
            for (int j = 0; j < 4; j++)
                fa[j] = *(const bf16x8*)&la[(64 * wm + 16 * j + lr) * 72 + ks * 32 + q * 8];
#pragma unroll
            for (int i = 0; i < 4; i++)
#pragma unroll
                for (int j = 0; j < 4; j++)
                    acc[i][j] = __builtin_amdgcn_mfma_f32_16x16x32_bf16(fw[i], fa[j], acc[i][j], 0, 0, 0);
        }
    }
#pragma unroll
    for (int i = 0; i < 4; i++) {
        const int nb = n0 + 64 * wn + 16 * i + q * 4;
        const float4 bb = *(const float4*)(bias + nb);
#pragma unroll
        for (int j = 0; j < 4; j++) {
            const int m = m0 + 64 * wm + 16 * j + lr;
            const int rowp = ((m & 1023) << 5) | (m >> 10);  // t*32 + b
            ushort4 o;
            o.x = f2bf_rne(acc[i][j][0] + bb.x);
            o.y = f2bf_rne(acc[i][j][1] + bb.y);
            o.z = f2bf_rne(acc[i][j][2] + bb.z);
            o.w = f2bf_rne(acc[i][j][3] + bb.w);
            *(ushort4*)(out + (size_t)rowp * N + nb) = o;
        }
    }
}

// ---------------- fused per-layer persistent kernel ----------------
// grid = 192 WGs x 512 thr, 158464 B dynamic LDS -> 1 WG/CU, all co-resident.
// WGs 0..63: persistent RNN (dir = b&1, bg = (b>>1)&1, cs = b>>2; 32 cols/WG).
//   h-exchange: producer sc1 packed stores (bypass L1/L2) -> flag; consumer
//   flag-poll -> 4 INDEPENDENT sc1 loads into regs (one pipelined IF$ round
//   trip) -> ds_write. NO cache-invalidating fences on the step path.
// WGs 64..191: gemm workers, 2 engines of 256 thr each, producing xpc chunks.
// ctl: [0..127] chunkready[c]*16, [128] rnnprog, [256..] stepflag[((d*2+bg)*16+cs)*16].
__global__ __launch_bounds__(512) void k_layer(
    const unsigned short* A,                  // layer input [32][1024][K] bf16
    const unsigned short* wih,                // [4096][K] bf16
    const float* bias,                        // [4096] f32 (b_ih+b_hh)
    const unsigned short* whh,                // [2][2048][512] bf16
    unsigned short* __restrict__ outb,        // [32][1024][1024] bf16
    unsigned short* xpc,                      // 2 chunks of [TC][32][4096] bf16
    unsigned short* hbuf,                     // [2dir][2par][32][512] bf16
    unsigned int* ctl, int K)
{
    extern __shared__ unsigned short smem[];
    const int tid = threadIdx.x;
    const int bid = blockIdx.x;
    unsigned int* chunkready = ctl;
    unsigned int* rnnprog = ctl + 128;
    unsigned int* stepflag = ctl + 256;

    if (bid < 64) {
        // =================== RNN role ===================
        unsigned short* lw = smem;                          // 128*520
        unsigned short* lh = smem + 128 * 520;              // 16*520
        float* lg = (float*)(smem + 128 * 520 + 16 * 520);  // 128*17
        const int dir = bid & 1;
        const int bg = (bid >> 1) & 1;
        const int cs = bid >> 2;
        const int c0 = cs * 32, b0 = bg * 16;
        const int lane = tid & 63, wv = tid >> 6;
        const int q = lane >> 4, lr = lane & 15;

        // one-time: stage weight slice into padded LDS
        for (int i = tid; i < 128 * 64; i += 512) {
            int row = i >> 6, ch = i & 63;
            int ty = row >> 5, cc = row & 31;
            ((uint4*)lw)[row * 65 + ch] =
                *(const uint4*)(whh + ((size_t)(dir * 2048 + ty * 512 + c0 + cc) * 512 + ch * 8));
        }
        const int xb = tid >> 5;   // batch in group 0..15
        const int xc = tid & 31;   // col in slice 0..31
        float cstate = 0.f;
        unsigned int* myflag = stepflag + ((dir * 2 + bg) * 16 + cs) * 16;
        const unsigned int* grpflag = stepflag + (dir * 2 + bg) * 256;
        __syncthreads();

        for (int s = 0; s < TT; ++s) {
            if ((s & (TC - 1)) == 0) {
                const int c = s >> 7;
                if (tid == 0) {
                    while (__hip_atomic_load(&chunkready[c * 16], __ATOMIC_RELAXED,
                                             __HIP_MEMORY_SCOPE_AGENT) < 128u)
                        __builtin_amdgcn_s_sleep(8);
                }
                __syncthreads();
                __builtin_amdgcn_fence(__ATOMIC_ACQUIRE, "agent");  // once per 128 steps
            }
            const unsigned short* xpb = xpc + (size_t)((s >> 7) & 1) * (TC * 32ull * 4096);
            const int t = dir ? (TT - 1 - s) : s;
            // prefetch xp (independent of h -> overlaps flag poll)
            const unsigned short* xpp = xpb + ((size_t)((s & (TC - 1)) * 32 + b0 + xb) * 4096)
                                       + dir * 2048 + c0 + xc;
            unsigned short x0 = xpp[0], x1 = xpp[512], x2 = xpp[1024], x3 = xpp[1536];

            if (s > 0) {
                // 1) poll group flags: lanes 0..15 of wave 0, parallel
                if (wv == 0) {
                    const unsigned int tgt = (unsigned int)s;
                    const unsigned int* fl = grpflag + (lane & 15) * 16;
                    for (;;) {
                        unsigned int v = (lane < 16)
                            ? __hip_atomic_load(fl, __ATOMIC_RELAXED, __HIP_MEMORY_SCOPE_AGENT)
                            : tgt;
                        if (__all((int)(v >= tgt))) break;
                    }
                }
                __syncthreads();
                // 2) gather h(s-1): 4 independent sc1 loads -> regs (one pipelined
                //    round trip), then LDS. Loads bypass L1/L2 -> always fresh.
                {
                    const int pp = (s & 1) ^ 1;
                    const unsigned short* hb = hbuf + ((size_t)(dir * 2 + pp) * 32 + b0) * 512;
                    const int ch = tid & 127, r0 = tid >> 7;
                    unsigned long long hv4[4];
#pragma unroll
                    for (int k2 = 0; k2 < 4; ++k2)
                        hv4[k2] = __hip_atomic_load(
                            (const unsigned long long*)(hb + (r0 + k2 * 4) * 512 + ch * 4),
                            __ATOMIC_RELAXED, __HIP_MEMORY_SCOPE_AGENT);
#pragma unroll
                    for (int k2 = 0; k2 < 4; ++k2)
                        *(unsigned long long*)&((unsigned int*)lh)[(r0 + k2 * 4) * 260 + ch * 2] = hv4[k2];
                }
                __syncthreads();
                // 3) MFMA: gates(s) partials
                f32x4 acc = (f32x4){0.f, 0.f, 0.f, 0.f};
                const unsigned short* lwr = lw + (16 * wv + lr) * 520;
                const unsigned short* lhr = lh + lr * 520;
#pragma unroll
                for (int ks = 0; ks < 16; ++ks) {
                    bf16x8 a = *(const bf16x8*)(lwr + ks * 32 + q * 8);
                    bf16x8 b = *(const bf16x8*)(lhr + ks * 32 + q * 8);
                    acc = __builtin_amdgcn_mfma_f32_16x16x32_bf16(a, b, acc, 0, 0, 0);
                }
#pragma unroll
                for (int r = 0; r < 4; ++r)
                    lg[(16 * wv + q * 4 + r) * 17 + lr] = acc[r];
                __syncthreads();
            }

            // cell update: thread owns (batch xb, col xc)
            unsigned short h16;
            {
                float gi = bf2f(x0) + (s > 0 ? lg[(0 * 32 + xc) * 17 + xb] : 0.f);
                float gf = bf2f(x1) + (s > 0 ? lg[(1 * 32 + xc) * 17 + xb] : 0.f);
                float gg = bf2f(x2) + (s > 0 ? lg[(2 * 32 + xc) * 17 + xb] : 0.f);
                float go = bf2f(x3) + (s > 0 ? lg[(3 * 32 + xc) * 17 + xb] : 0.f);
                float ig = sigm(gi), fg = sigm(gf), cg = tanhs(gg), og = sigm(go);
                cstate = fg * cstate + ig * cg;
                float h = og * tanhs(cstate);
                h16 = f2bf_rne(h);
                // h -> hbuf: sc1 packed stores (bypass L1/L2), fire-and-forget
                unsigned int hv = h16;
                unsigned int other = __shfl_xor((int)hv, 1);
                if ((tid & 1) == 0) {
                    size_t idx = ((size_t)(dir * 2 + (s & 1)) * 32 + b0 + xb) * 512 + c0 + xc;
                    unsigned int packed = hv | (other << 16);
                    __hip_atomic_store((unsigned int*)hbuf + (idx >> 1), packed,
                                       __ATOMIC_RELAXED, __HIP_MEMORY_SCOPE_AGENT);
                }
            }
            // barrier drains every thread's h stores (vmcnt(0) before s_barrier)
            __syncthreads();
            if (tid == 0)
                __hip_atomic_store(myflag, (unsigned int)(s + 1),
                                   __ATOMIC_RELAXED, __HIP_MEMORY_SCOPE_AGENT);
            if ((s & (TC - 1)) == (TC - 1) && tid == 0)
                __hip_atomic_fetch_add(rnnprog, 1u, __ATOMIC_RELAXED, __HIP_MEMORY_SCOPE_AGENT);
            // layer output off the critical path (drains during next step's poll)
            outb[((size_t)(b0 + xb) * TT + t) * 1024 + dir * 512 + c0 + xc] = h16;
        }
    } else {
        // =================== GEMM worker role ===================
        const int w = bid - 64;               // 0..127
        const int engine = tid >> 8;          // 0/1
        const int etid = tid & 255;
        unsigned short* lw = smem + engine * 18432;   // 128*72 shorts
        unsigned short* la = lw + 9216;
        const int lane = etid & 63, wv = etid >> 6;
        const int q = lane >> 4, lr = lane & 15;
        const int wn = wv & 1, wm = wv >> 1;
        const int srow = etid >> 1, shalf = etid & 1;

        for (int c = 0; c < 8; ++c) {
            if (c >= 2) {
                // back-pressure: don't overwrite buffer until rnn consumed chunk c-2
                if (tid == 0) {
                    unsigned int tgt = 64u * (unsigned int)(c - 1);
                    while (__hip_atomic_load(rnnprog, __ATOMIC_RELAXED,
                                             __HIP_MEMORY_SCOPE_AGENT) < tgt)
                        __builtin_amdgcn_s_sleep(8);
                }
                __syncthreads();
            }
            unsigned short* xpb = xpc + (size_t)(c & 1) * (TC * 32ull * 4096);
            for (int jt = 0; jt < 4; ++jt) {
                const int tau = (w * 2 + engine) + 256 * jt;    // 0..1023
                const int dir = tau >> 9, rem = tau & 511;
                const int b = rem >> 4, nx = rem & 15;
                const int t0 = dir ? (TT - c * TC - TC) : (c * TC);
                const int n0 = dir * 2048 + nx * 128;
                const int m0 = b * TT + t0;
                f32x4 acc[4][4];
#pragma unroll
                for (int i = 0; i < 4; i++)
#pragma unroll
                    for (int j = 0; j < 4; j++) acc[i][j] = (f32x4){0.f, 0.f, 0.f, 0.f};

                for (int k0 = 0; k0 < K; k0 += 64) {
                    const uint4* gw = (const uint4*)(wih + (size_t)(n0 + srow) * K + k0 + shalf * 32);
                    const uint4* ga = (const uint4*)(A + (size_t)(m0 + srow) * K + k0 + shalf * 32);
                    uint4 wld[4], ald[4];
#pragma unroll
                    for (int j = 0; j < 4; j++) { wld[j] = gw[j]; ald[j] = ga[j]; }
                    __syncthreads();
#pragma unroll
                    for (int j = 0; j < 4; j++) {
                        ((uint4*)lw)[srow * 9 + shalf * 4 + j] = wld[j];
                        ((uint4*)la)[srow * 9 + shalf * 4 + j] = ald[j];
                    }
                    __syncthreads();
#pragma unroll
                    for (int ks = 0; ks < 2; ks++) {
                        bf16x8 fw[4], fa[4];
#pragma unroll
                        for (int i = 0; i < 4; i++)
                            fw[i] = *(const bf16x8*)&lw[(64 * wn + 16 * i + lr) * 72 + ks * 32 + q * 8];
#pragma unroll
                        for (int j = 0; j < 4; j++)
                            fa[j] = *(const bf16x8*)&la[(64 * wm + 16 * j + lr) * 72 + ks * 32 + q * 8];
#pragma unroll
                        for (int i = 0; i < 4; i++)
#pragma unroll
                            for (int j = 0; j < 4; j++)
                                acc[i][j] = __builtin_amdgcn_mfma_f32_16x16x32_bf16(fw[i], fa[j], acc[i][j], 0, 0, 0);
                    }
                }
#pragma unroll
                for (int i = 0; i < 4; i++) {
                    const int nb = n0 + 64 * wn + 16 * i + q * 4;
                    const float4 bb = *(const float4*)(bias + nb);
#pragma unroll
                    for (int j = 0; j < 4; j++) {
                        const int dm = 64 * wm + 16 * j + lr;          // t = t0 + dm
                        const int islot = dir ? (TC - 1 - dm) : dm;    // step-within-chunk
                        ushort4 o;
                        o.x = f2bf_rne(acc[i][j][0] + bb.x);
                        o.y = f2bf_rne(acc[i][j][1] + bb.y);
                        o.z = f2bf_rne(acc[i][j][2] + bb.z);
                        o.w = f2bf_rne(acc[i][j][3] + bb.w);
                        *(ushort4*)(xpb + ((size_t)islot * 32 + b) * 4096 + nb) = o;
                    }
                }
            }
            // publish chunk: write back dirty L2 lines, then signal
            __builtin_amdgcn_fence(__ATOMIC_RELEASE, "agent");
            __syncthreads();
            if (tid == 0)
                __hip_atomic_fetch_add(&chunkready[c * 16], 1u,
                                       __ATOMIC_RELEASE, __HIP_MEMORY_SCOPE_AGENT);
        }
    }
}

// ---------------- rnn2: unidirectional, H=64; register-resident gates ----------------
__global__ __launch_bounds__(512) void k_rnn2(
    const unsigned short* __restrict__ xp2,   // [t*32+b][256] bf16
    const unsigned short* __restrict__ whh2,  // [256][64] bf16
    float* __restrict__ out)                  // [B][T][64] f32
{
    __shared__ unsigned short lw[256 * 72];
    __shared__ unsigned short lh[2][16 * 68];
    const int tid = threadIdx.x;
    const int b0 = blockIdx.x * 16;
    const int lane = tid & 63, wv = tid >> 6;
    const int q = lane >> 4, l = lane & 15;

    for (int i = tid; i < 256 * 8; i += 512) {
        int row = i >> 3, ch = i & 7;
        ((uint4*)lw)[row * 9 + ch] = *(const uint4*)(whh2 + (size_t)row * 64 + ch * 8);
    }
    __syncthreads();

    if (wv < 4) {
        const int cbase = wv * 16 + q * 4;
        float cst[4] = {0.f, 0.f, 0.f, 0.f};
        for (int s = 0; s < TT; ++s) {
            const unsigned short* xr = xp2 + (size_t)(s * 32 + b0 + l) * 256 + cbase;
            ushort4 xv0 = *(const ushort4*)(xr);
            ushort4 xv1 = *(const ushort4*)(xr + 64);
            ushort4 xv2 = *(const ushort4*)(xr + 128);
            ushort4 xv3 = *(const ushort4*)(xr + 192);
            f32x4 acc[4];
            if (s > 0) {
                const unsigned short* lhr = lh[(s & 1) ^ 1] + l * 68;
                bf16x8 hb0 = *(const bf16x8*)(lhr + q * 8);
                bf16x8 hb1 = *(const bf16x8*)(lhr + 32 + q * 8);
#pragma unroll
                for (int ty = 0; ty < 4; ++ty) {
                    const unsigned short* lwr = lw + (size_t)(ty * 64 + wv * 16 + l) * 72;
                    bf16x8 a0 = *(const bf16x8*)(lwr + q * 8);
                    bf16x8 a1 = *(const bf16x8*)(lwr + 32 + q * 8);
                    f32x4 tacc = (f32x4){0.f, 0.f, 0.f, 0.f};
                    tacc = __builtin_amdgcn_mfma_f32_16x16x32_bf16(a0, hb0, tacc, 0, 0, 0);
                    tacc = __builtin_amdgcn_mfma_f32_16x16x32_bf16(a1, hb1, tacc, 0, 0, 0);
                    acc[ty] = tacc;
                }
            } else {
#pragma unroll
                for (int ty = 0; ty < 4; ++ty) acc[ty] = (f32x4){0.f, 0.f, 0.f, 0.f};
            }
            ushort4 ho; float4 oo;
            const unsigned short* xs0 = (const unsigned short*)&xv0;
            const unsigned short* xs1 = (const unsigned short*)&xv1;
            const unsigned short* xs2 = (const unsigned short*)&xv2;
            const unsigned short* xs3 = (const unsigned short*)&xv3;
#pragma unroll
            for (int r = 0; r < 4; ++r) {
                float gi = bf2f(xs0[r]) + acc[0][r];
                float gf = bf2f(xs1[r]) + acc[1][r];
                float gg = bf2f(xs2[r]) + acc[2][r];
                float go = bf2f(xs3[r]) + acc[3][r];
                float ig = sigm(gi), fg = sigm(gf), cg = tanhs(gg), og = sigm(go);
                cst[r] = fg * cst[r] + ig * cg;
                float h = og * tanhs(cst[r]);
                ((float*)&oo)[r] = 40.f * h;
                ((unsigned short*)&ho)[r] = f2bf_rne(h);
            }
            *(ushort4*)(lh[s & 1] + l * 68 + cbase) = ho;
            *(float4*)(out + ((size_t)(b0 + l) * TT + s) * 64 + cbase) = oo;
            __syncthreads();
        }
    } else {
        for (int s = 0; s < TT; ++s) __syncthreads();
    }
}

// ---------------- host launch ----------------
extern "C" void kernel_launch(void* const* d_in, const int* in_sizes, int n_in,
                              void* d_out, int out_size, void* d_ws, size_t ws_size,
                              hipStream_t stream) {
    (void)in_sizes; (void)n_in; (void)out_size;
    const float* x     = (const float*)d_in[0];
    const float* Wih0  = (const float*)d_in[1];
    const float* Whh0  = (const float*)d_in[2];
    const float* bih0  = (const float*)d_in[3];
    const float* bhh0  = (const float*)d_in[4];
    const float* Wih12 = (const float*)d_in[5];
    const float* Whh12 = (const float*)d_in[6];
    const float* bih12 = (const float*)d_in[7];
    const float* bhh12 = (const float*)d_in[8];
    const float* Wih2  = (const float*)d_in[9];
    const float* Whh2  = (const float*)d_in[10];
    const float* bih2  = (const float*)d_in[11];
    const float* bhh2  = (const float*)d_in[12];
    float* out = (float*)d_out;

    char* ws = (char*)d_ws;
    size_t off = 0;
    auto alloc = [&](size_t sz) { char* p = ws + off; off += (sz + 255) & ~(size_t)255; return p; };
    unsigned short* actA  = (unsigned short*)alloc(33554432ull * 2);        // 64 MB
    unsigned short* actB  = (unsigned short*)alloc(33554432ull * 2);        // 64 MB
    unsigned short* xpc   = (unsigned short*)alloc(2ull * TC * 32 * 4096 * 2); // 64 MB (dbuf)
    unsigned short* xbf   = (unsigned short*)alloc(2097152ull * 2);
    unsigned short* wihc  = (unsigned short*)alloc(4194304ull * 2);         // per-layer W_ih
    unsigned short* whhc  = (unsigned short*)alloc(2097152ull * 2);         // per-layer W_hh
    unsigned short* wih2b = (unsigned short*)alloc(262144ull * 2);
    unsigned short* whh2b = (unsigned short*)alloc(16384ull * 2);
    float* bs  = (float*)alloc(4096 * 4);
    float* bs2 = (float*)alloc(256 * 4);
    unsigned short* hbuf = (unsigned short*)alloc(2ull * 2 * 32 * 512 * 2);
    unsigned int* ctrl = (unsigned int*)alloc(16384);

    if (ws_size < off) {
        fprintf(stderr, "[kernel_launch] ws_size=%zu < needed=%zu — aborting cleanly\n", ws_size, off);
        return;
    }

    auto cvt = [&](const float* s, unsigned short* d, int n) {
        int n4 = n / 4;
        k_f2bf<<<(n4 + 255) / 256, 256, 0, stream>>>(s, d, n4);
    };
    cvt(x, xbf, 2097152);
    cvt(Wih2, wih2b, 262144);
    cvt(Whh2, whh2b, 16384);
    k_bsum<<<1, 256, 0, stream>>>(bih2, bhh2, bs2, 256);

    hipError_t rc = hipFuncSetAttribute(reinterpret_cast<const void*>(k_layer),
                                        hipFuncAttributeMaxDynamicSharedMemorySize, 160 * 1024);
    if (rc != hipSuccess) fprintf(stderr, "[kernel_launch] hipFuncSetAttribute rc=%d\n", (int)rc);
    const size_t layer_lds = (size_t)(128 * 520 + 16 * 520) * 2 + (size_t)128 * 17 * 4;  // 158464 B

    for (int l = 0; l < 3; ++l) {
        const unsigned short* Abuf;
        unsigned short* Obuf;
        int K;
        if (l == 0) {
            cvt(Wih0, wihc, 262144);
            cvt(Whh0, whhc, 2097152);
            k_bsum<<<16, 256, 0, stream>>>(bih0, bhh0, bs, 4096);
            Abuf = xbf; Obuf = actA; K = 64;
        } else {
            cvt(Wih12 + (size_t)(l - 1) * 4194304, wihc, 4194304);
            cvt(Whh12 + (size_t)(l - 1) * 2097152, whhc, 2097152);
            k_bsum<<<16, 256, 0, stream>>>(bih12 + (l - 1) * 4096, bhh12 + (l - 1) * 4096, bs, 4096);
            Abuf = (l == 1) ? actA : actB;
            Obuf = (l == 1) ? actB : actA;
            K = 1024;
        }
        hipMemsetAsync(ctrl, 0, 16384, stream);
        k_layer<<<192, 512, layer_lds, stream>>>(Abuf, wihc, bs, whhc, Obuf, xpc, hbuf, ctrl, K);
    }

    // rnn2: projection (16 MB, fits in xpc) then register-resident scan
    k_gemm<<<dim3(2, 256), 256, 0, stream>>>(actA, wih2b, bs2, xpc, 256, 1024);
    k_rnn2<<<2, 512, 0, stream>>>(xpc, whh2b, out);
}